// Round 1
// baseline (10949.681 us; speedup 1.0000x reference)
//
#include <hip/hip_runtime.h>

#define NIN 512
#define NOUT 256

// ---------------- GEMM: h[M][256] = x[M][512] @ W[256][512]^T + b ----------
// 64x64 tile, BK=32, 256 threads, 4x4 register blocking.
// LDS stores A,B transposed ([k][m]/[k][n]) so the inner loop reads float4.
__global__ __launch_bounds__(256) void gemm_kernel(
    const float* __restrict__ x, const float* __restrict__ W,
    const float* __restrict__ bias, float* __restrict__ h, int M) {
  const int BM = 64, BN = 64, BK = 32;
  __shared__ float As[BK][BM + 4];
  __shared__ float Bs[BK][BN + 4];
  const int tid = threadIdx.x;
  const int tx = tid & 15;   // output col group
  const int ty = tid >> 4;   // output row group
  const int m0 = blockIdx.x * BM;
  const int n0 = blockIdx.y * BN;

  float acc[4][4] = {};

  const int kk   = (tid & 7) * 4;  // k offset within tile (0..28)
  const int mrow = tid >> 3;       // 0..31

  for (int k0 = 0; k0 < NIN; k0 += BK) {
    // stage A tile (64 rows x 32 k), transposed into As[k][m]
#pragma unroll
    for (int p = 0; p < 2; ++p) {
      int m = mrow + p * 32;
      float4 v = make_float4(0.f, 0.f, 0.f, 0.f);
      if (m0 + m < M)
        v = *reinterpret_cast<const float4*>(x + (size_t)(m0 + m) * NIN + k0 + kk);
      As[kk + 0][m] = v.x; As[kk + 1][m] = v.y;
      As[kk + 2][m] = v.z; As[kk + 3][m] = v.w;
    }
    // stage B tile: Bs[k][n] = W[n0+n][k0+k]
#pragma unroll
    for (int p = 0; p < 2; ++p) {
      int n = mrow + p * 32;
      float4 v = *reinterpret_cast<const float4*>(W + (size_t)(n0 + n) * NIN + k0 + kk);
      Bs[kk + 0][n] = v.x; Bs[kk + 1][n] = v.y;
      Bs[kk + 2][n] = v.z; Bs[kk + 3][n] = v.w;
    }
    __syncthreads();

#pragma unroll
    for (int k = 0; k < BK; ++k) {
      float4 a = *reinterpret_cast<const float4*>(&As[k][ty * 4]);
      float4 b = *reinterpret_cast<const float4*>(&Bs[k][tx * 4]);
      float av[4] = {a.x, a.y, a.z, a.w};
      float bv[4] = {b.x, b.y, b.z, b.w};
#pragma unroll
      for (int i = 0; i < 4; ++i)
#pragma unroll
        for (int j = 0; j < 4; ++j)
          acc[i][j] += av[i] * bv[j];
    }
    __syncthreads();
  }

  // epilogue: add bias, store float4 per row
  const int ncol = n0 + tx * 4;
  float4 bv = *reinterpret_cast<const float4*>(bias + ncol);
#pragma unroll
  for (int i = 0; i < 4; ++i) {
    int m = m0 + ty * 4 + i;
    if (m >= M) continue;
    float4 o;
    o.x = acc[i][0] + bv.x;
    o.y = acc[i][1] + bv.y;
    o.z = acc[i][2] + bv.z;
    o.w = acc[i][3] + bv.w;
    *reinterpret_cast<float4*>(h + (size_t)m * NOUT + ncol) = o;
  }
}

// ---------------- scatter: out[rows[e]] += vals[e] * h[cols[e]] ------------
// one wave (64 lanes) per edge; each lane owns 4 channels (float4 gather).
__global__ __launch_bounds__(256) void scatter_kernel(
    const float* __restrict__ h, const int* __restrict__ rows,
    const int* __restrict__ cols, const float* __restrict__ vals,
    float* __restrict__ out, int E) {
  int wave = (int)((blockIdx.x * (size_t)blockDim.x + threadIdx.x) >> 6);
  if (wave >= E) return;
  int lane = threadIdx.x & 63;

  int c = cols[wave];
  int r = rows[wave];
  float v = vals[wave];

  float4 hv = *reinterpret_cast<const float4*>(h + (size_t)c * NOUT + lane * 4);
  float* dst = out + (size_t)r * NOUT + lane * 4;

  // HW global_atomic_add_f32 (avoid CAS loop)
  unsafeAtomicAdd(dst + 0, hv.x * v);
  unsafeAtomicAdd(dst + 1, hv.y * v);
  unsafeAtomicAdd(dst + 2, hv.z * v);
  unsafeAtomicAdd(dst + 3, hv.w * v);
}

extern "C" void kernel_launch(void* const* d_in, const int* in_sizes, int n_in,
                              void* d_out, int out_size, void* d_ws, size_t ws_size,
                              hipStream_t stream) {
  const float* x        = (const float*)d_in[0];
  const int*   adj_rows = (const int*)d_in[1];
  const int*   adj_cols = (const int*)d_in[2];
  const float* adj_vals = (const float*)d_in[3];
  const float* W        = (const float*)d_in[4];
  const float* b        = (const float*)d_in[5];
  float* out = (float*)d_out;

  const int M = in_sizes[0] / NIN;   // 100000
  const int E = in_sizes[1];         // 3200000

  float* h = (float*)d_ws;           // M*NOUT floats = 102.4 MB

  // out accumulates via atomics -> must start at zero every call
  hipMemsetAsync(d_out, 0, (size_t)out_size * sizeof(float), stream);

  dim3 ggrid((M + 63) / 64, NOUT / 64);
  gemm_kernel<<<ggrid, 256, 0, stream>>>(x, W, b, h, M);

  int blocks = (E + 3) / 4;  // 4 waves (edges) per 256-thread block
  scatter_kernel<<<blocks, 256, 0, stream>>>(h, adj_rows, adj_cols, adj_vals, out, E);
}

// Round 2
// 1159.384 us; speedup vs baseline: 9.4444x; 9.4444x over previous
//
#include <hip/hip_runtime.h>

#define NIN 512
#define NOUT 256

// ---------------- GEMM: h[M][256] = x[M][512] @ W[256][512]^T + b ----------
__global__ __launch_bounds__(256) void gemm_kernel(
    const float* __restrict__ x, const float* __restrict__ W,
    const float* __restrict__ bias, float* __restrict__ h, int M) {
  const int BM = 64, BN = 64, BK = 32;
  __shared__ float As[BK][BM + 4];
  __shared__ float Bs[BK][BN + 4];
  const int tid = threadIdx.x;
  const int tx = tid & 15;
  const int ty = tid >> 4;
  const int m0 = blockIdx.x * BM;
  const int n0 = blockIdx.y * BN;

  float acc[4][4] = {};

  const int kk   = (tid & 7) * 4;
  const int mrow = tid >> 3;

  for (int k0 = 0; k0 < NIN; k0 += BK) {
#pragma unroll
    for (int p = 0; p < 2; ++p) {
      int m = mrow + p * 32;
      float4 v = make_float4(0.f, 0.f, 0.f, 0.f);
      if (m0 + m < M)
        v = *reinterpret_cast<const float4*>(x + (size_t)(m0 + m) * NIN + k0 + kk);
      As[kk + 0][m] = v.x; As[kk + 1][m] = v.y;
      As[kk + 2][m] = v.z; As[kk + 3][m] = v.w;
    }
#pragma unroll
    for (int p = 0; p < 2; ++p) {
      int n = mrow + p * 32;
      float4 v = *reinterpret_cast<const float4*>(W + (size_t)(n0 + n) * NIN + k0 + kk);
      Bs[kk + 0][n] = v.x; Bs[kk + 1][n] = v.y;
      Bs[kk + 2][n] = v.z; Bs[kk + 3][n] = v.w;
    }
    __syncthreads();

#pragma unroll
    for (int k = 0; k < BK; ++k) {
      float4 a = *reinterpret_cast<const float4*>(&As[k][ty * 4]);
      float4 b = *reinterpret_cast<const float4*>(&Bs[k][tx * 4]);
      float av[4] = {a.x, a.y, a.z, a.w};
      float bv[4] = {b.x, b.y, b.z, b.w};
#pragma unroll
      for (int i = 0; i < 4; ++i)
#pragma unroll
        for (int j = 0; j < 4; ++j)
          acc[i][j] += av[i] * bv[j];
    }
    __syncthreads();
  }

  const int ncol = n0 + tx * 4;
  float4 bv = *reinterpret_cast<const float4*>(bias + ncol);
#pragma unroll
  for (int i = 0; i < 4; ++i) {
    int m = m0 + ty * 4 + i;
    if (m >= M) continue;
    float4 o;
    o.x = acc[i][0] + bv.x;
    o.y = acc[i][1] + bv.y;
    o.z = acc[i][2] + bv.z;
    o.w = acc[i][3] + bv.w;
    *reinterpret_cast<float4*>(h + (size_t)m * NOUT + ncol) = o;
  }
}

// ---------------- CSR build: histogram --------------------------------------
__global__ __launch_bounds__(256) void hist_kernel(
    const int* __restrict__ rows, int* __restrict__ offs, int E) {
  int i = blockIdx.x * blockDim.x + threadIdx.x;
  int stride = gridDim.x * blockDim.x;
  for (; i < E; i += stride) atomicAdd(&offs[rows[i]], 1);
}

// ---------------- exclusive scan (3-kernel hierarchical) --------------------
// scanA: each block scans 1024 elements (256 threads x 4), in place, exclusive;
//        block total -> blockSums[b] (if non-null).
__global__ __launch_bounds__(256) void scanA_kernel(
    int* __restrict__ data, int* __restrict__ blockSums, int n) {
  __shared__ int s[256];
  const int t = threadIdx.x;
  const int base = blockIdx.x * 1024 + t * 4;
  int v[4];
#pragma unroll
  for (int j = 0; j < 4; ++j) v[j] = (base + j < n) ? data[base + j] : 0;
  int local = v[0] + v[1] + v[2] + v[3];
  s[t] = local;
  __syncthreads();
  // Hillis-Steele inclusive scan over s[256]
  for (int off = 1; off < 256; off <<= 1) {
    int x = (t >= off) ? s[t - off] : 0;
    __syncthreads();
    s[t] += x;
    __syncthreads();
  }
  int excl = s[t] - local;
  if (t == 255 && blockSums) blockSums[blockIdx.x] = s[255];
  int run = excl;
#pragma unroll
  for (int j = 0; j < 4; ++j) {
    int nv = v[j];
    if (base + j < n) data[base + j] = run;
    run += nv;
  }
}

__global__ __launch_bounds__(256) void scanC_kernel(
    int* __restrict__ data, const int* __restrict__ blockSums, int n) {
  int i = blockIdx.x * blockDim.x + threadIdx.x;
  if (i < n) data[i] += blockSums[i >> 10];
}

// ---------------- placement: sorted (col,val) by row -------------------------
// cursor trick: after this, offs[r] = end offset of row r.
__global__ __launch_bounds__(256) void place_kernel(
    const int* __restrict__ rows, const int* __restrict__ cols,
    const float* __restrict__ vals, int* __restrict__ offs,
    int* __restrict__ scol, float* __restrict__ sval, int E) {
  int i = blockIdx.x * blockDim.x + threadIdx.x;
  int stride = gridDim.x * blockDim.x;
  for (; i < E; i += stride) {
    int r = rows[i];
    int pos = atomicAdd(&offs[r], 1);
    scol[pos] = cols[i];
    sval[pos] = vals[i];
  }
}

// ---------------- gather-reduce: one wave per output row --------------------
__global__ __launch_bounds__(256) void accum_kernel(
    const float* __restrict__ h, const int* __restrict__ scol,
    const float* __restrict__ sval, const int* __restrict__ offs,
    float* __restrict__ out, int M) {
  int wid = (int)((blockIdx.x * (size_t)blockDim.x + threadIdx.x) >> 6);
  if (wid >= M) return;
  const int lane = threadIdx.x & 63;

  int start = (wid == 0) ? 0 : offs[wid - 1];
  int end = offs[wid];

  float4 acc = make_float4(0.f, 0.f, 0.f, 0.f);
  int e = start;
  if (e < end) {
    int c = scol[e];
    float v = sval[e];
    while (true) {
      int cn = 0; float vn = 0.f;
      if (e + 1 < end) { cn = scol[e + 1]; vn = sval[e + 1]; }
      float4 hv = *reinterpret_cast<const float4*>(h + (size_t)c * NOUT + lane * 4);
      acc.x += v * hv.x; acc.y += v * hv.y;
      acc.z += v * hv.z; acc.w += v * hv.w;
      if (++e >= end) break;
      c = cn; v = vn;
    }
  }
  *reinterpret_cast<float4*>(out + (size_t)wid * NOUT + lane * 4) = acc;
}

// ---------------- fallback: atomic scatter (round-1 path) -------------------
__global__ __launch_bounds__(256) void scatter_kernel(
    const float* __restrict__ h, const int* __restrict__ rows,
    const int* __restrict__ cols, const float* __restrict__ vals,
    float* __restrict__ out, int E) {
  int wave = (int)((blockIdx.x * (size_t)blockDim.x + threadIdx.x) >> 6);
  if (wave >= E) return;
  int lane = threadIdx.x & 63;
  int c = cols[wave];
  int r = rows[wave];
  float v = vals[wave];
  float4 hv = *reinterpret_cast<const float4*>(h + (size_t)c * NOUT + lane * 4);
  float* dst = out + (size_t)r * NOUT + lane * 4;
  unsafeAtomicAdd(dst + 0, hv.x * v);
  unsafeAtomicAdd(dst + 1, hv.y * v);
  unsafeAtomicAdd(dst + 2, hv.z * v);
  unsafeAtomicAdd(dst + 3, hv.w * v);
}

extern "C" void kernel_launch(void* const* d_in, const int* in_sizes, int n_in,
                              void* d_out, int out_size, void* d_ws, size_t ws_size,
                              hipStream_t stream) {
  const float* x        = (const float*)d_in[0];
  const int*   adj_rows = (const int*)d_in[1];
  const int*   adj_cols = (const int*)d_in[2];
  const float* adj_vals = (const float*)d_in[3];
  const float* W        = (const float*)d_in[4];
  const float* b        = (const float*)d_in[5];
  float* out = (float*)d_out;

  const int M = in_sizes[0] / NIN;   // 100000
  const int E = in_sizes[1];         // 3200000

  // workspace layout
  float* h = (float*)d_ws;                                   // M*NOUT floats
  size_t off_h = (size_t)M * NOUT;
  int*   scol = (int*)((float*)d_ws + off_h);                // E ints
  float* sval = (float*)(scol + E);                          // E floats
  int*   offs = (int*)(sval + E);                            // M+1 ints
  int*   blockSums = offs + (M + 1);                         // <=128 ints

  const int scanBlocks = (M + 1023) / 1024;                  // 98
  size_t needed = (off_h + 2 * (size_t)E + (size_t)(M + 1) + (scanBlocks + 8)) * 4;

  dim3 ggrid((M + 63) / 64, NOUT / 64);
  gemm_kernel<<<ggrid, 256, 0, stream>>>(x, W, b, h, M);

  if (ws_size >= needed) {
    // ---- CSR build + atomic-free gather-reduce ----
    hipMemsetAsync(offs, 0, (size_t)(M + 1 + scanBlocks + 8) * sizeof(int), stream);
    hist_kernel<<<2048, 256, 0, stream>>>(adj_rows, offs, E);
    scanA_kernel<<<scanBlocks, 256, 0, stream>>>(offs, blockSums, M);
    scanA_kernel<<<1, 256, 0, stream>>>(blockSums, nullptr, scanBlocks);
    scanC_kernel<<<(M + 255) / 256, 256, 0, stream>>>(offs, blockSums, M);
    place_kernel<<<2048, 256, 0, stream>>>(adj_rows, adj_cols, adj_vals, offs,
                                           scol, sval, E);
    int ablocks = (int)(((size_t)M * 64 + 255) / 256);
    accum_kernel<<<ablocks, 256, 0, stream>>>(h, scol, sval, offs, out, M);
  } else {
    // ---- fallback: atomic scatter ----
    hipMemsetAsync(d_out, 0, (size_t)out_size * sizeof(float), stream);
    int blocks = (E + 3) / 4;
    scatter_kernel<<<blocks, 256, 0, stream>>>(h, adj_rows, adj_cols, adj_vals,
                                               out, E);
  }
}

// Round 3
// 626.774 us; speedup vs baseline: 17.4699x; 1.8498x over previous
//
#include <hip/hip_runtime.h>

#define NIN 512
#define NOUT 256

typedef __attribute__((ext_vector_type(8))) __bf16 bf16x8;
typedef __attribute__((ext_vector_type(4))) float f32x4;

__device__ __forceinline__ ushort f2bf(float f) {
  uint u = __builtin_bit_cast(uint, f);
  uint r = (u + 0x7FFFu + ((u >> 16) & 1u)) >> 16;  // RNE
  return (ushort)r;
}
__device__ __forceinline__ uint pk2(float a, float b) {
  return (uint)f2bf(a) | ((uint)f2bf(b) << 16);
}
__device__ __forceinline__ float bf2f(ushort u) {
  return __builtin_bit_cast(float, (uint)u << 16);
}

// ---------------- GEMM: h[M][256] = bf16(x[M][512] @ W[256][512]^T + b) ----
// 512 threads = 8 waves; BM=128 (16 rows/wave), BN=256 (full), BK=32.
// LDS tiles stored bf16 with padded row stride 40 (80B) to break conflicts.
__global__ __launch_bounds__(512) void gemm_kernel(
    const float* __restrict__ x, const float* __restrict__ W,
    const float* __restrict__ bias, ushort* __restrict__ h, int M) {
  __shared__ ushort a_lds[128 * 40];  // [row][k] stride 40
  __shared__ ushort b_lds[256 * 40];  // [n][k]   stride 40

  const int t = threadIdx.x;
  const int l = t & 63;
  const int wv = t >> 6;          // wave 0..7
  const int m0 = blockIdx.x * 128;

  const int lrow = l & 15;        // fragment row/col index
  const int lk = (l >> 4) * 8;    // fragment k offset

  f32x4 acc[16];
#pragma unroll
  for (int i = 0; i < 16; ++i) acc[i] = (f32x4){0.f, 0.f, 0.f, 0.f};

  float biasr[16];
#pragma unroll
  for (int nt = 0; nt < 16; ++nt) biasr[nt] = bias[nt * 16 + lrow];

  // staging coords
  const int arow = t >> 2;          // 0..127
  const int akc = (t & 3) * 8;      // 0,8,16,24
  const int brow = t >> 1;          // 0..255
  const int bkc = (t & 1) * 16;     // 0,16

  for (int k0 = 0; k0 < NIN; k0 += 32) {
    // ---- stage A: 128 rows x 32 k, fp32 -> bf16
    {
      float4 v0 = make_float4(0.f, 0.f, 0.f, 0.f), v1 = v0;
      if (m0 + arow < M) {
        const float4* xs =
            reinterpret_cast<const float4*>(x + (size_t)(m0 + arow) * NIN + k0 + akc);
        v0 = xs[0];
        v1 = xs[1];
      }
      uint4 p;
      p.x = pk2(v0.x, v0.y); p.y = pk2(v0.z, v0.w);
      p.z = pk2(v1.x, v1.y); p.w = pk2(v1.z, v1.w);
      *reinterpret_cast<uint4*>(&a_lds[arow * 40 + akc]) = p;
    }
    // ---- stage B: 256 rows x 32 k of W, fp32 -> bf16
    {
      const float4* wsrc =
          reinterpret_cast<const float4*>(W + (size_t)brow * NIN + k0 + bkc);
      float4 w0 = wsrc[0], w1 = wsrc[1], w2 = wsrc[2], w3 = wsrc[3];
      uint4 p0, p1;
      p0.x = pk2(w0.x, w0.y); p0.y = pk2(w0.z, w0.w);
      p0.z = pk2(w1.x, w1.y); p0.w = pk2(w1.z, w1.w);
      p1.x = pk2(w2.x, w2.y); p1.y = pk2(w2.z, w2.w);
      p1.z = pk2(w3.x, w3.y); p1.w = pk2(w3.z, w3.w);
      *reinterpret_cast<uint4*>(&b_lds[brow * 40 + bkc]) = p0;
      *reinterpret_cast<uint4*>(&b_lds[brow * 40 + bkc + 8]) = p1;
    }
    __syncthreads();

    // ---- MFMA: each wave computes its 16 rows x 256 cols
    bf16x8 af = *reinterpret_cast<const bf16x8*>(&a_lds[(wv * 16 + lrow) * 40 + lk]);
#pragma unroll
    for (int nt = 0; nt < 16; ++nt) {
      bf16x8 bf_ = *reinterpret_cast<const bf16x8*>(&b_lds[(nt * 16 + lrow) * 40 + lk]);
      acc[nt] = __builtin_amdgcn_mfma_f32_16x16x32_bf16(af, bf_, acc[nt], 0, 0, 0);
    }
    __syncthreads();
  }

  // ---- epilogue: +bias, cvt bf16, store
  const int mbase = m0 + wv * 16 + (l >> 4) * 4;
#pragma unroll
  for (int r = 0; r < 4; ++r) {
    int m = mbase + r;
    if (m >= M) continue;
#pragma unroll
    for (int nt = 0; nt < 16; ++nt)
      h[(size_t)m * NOUT + nt * 16 + lrow] = f2bf(acc[nt][r] + biasr[nt]);
  }
}

// ---------------- CSR build: histogram --------------------------------------
__global__ __launch_bounds__(256) void hist_kernel(
    const int* __restrict__ rows, int* __restrict__ offs, int E) {
  int i = blockIdx.x * blockDim.x + threadIdx.x;
  int stride = gridDim.x * blockDim.x;
  for (; i < E; i += stride) atomicAdd(&offs[rows[i]], 1);
}

// ---------------- exclusive scan (hierarchical) ------------------------------
__global__ __launch_bounds__(256) void scanA_kernel(
    int* __restrict__ data, int* __restrict__ blockSums, int n) {
  __shared__ int s[256];
  const int t = threadIdx.x;
  const int base = blockIdx.x * 1024 + t * 4;
  int v[4];
#pragma unroll
  for (int j = 0; j < 4; ++j) v[j] = (base + j < n) ? data[base + j] : 0;
  int local = v[0] + v[1] + v[2] + v[3];
  s[t] = local;
  __syncthreads();
  for (int off = 1; off < 256; off <<= 1) {
    int x = (t >= off) ? s[t - off] : 0;
    __syncthreads();
    s[t] += x;
    __syncthreads();
  }
  int excl = s[t] - local;
  if (t == 255 && blockSums) blockSums[blockIdx.x] = s[255];
  int run = excl;
#pragma unroll
  for (int j = 0; j < 4; ++j) {
    int nv = v[j];
    if (base + j < n) data[base + j] = run;
    run += nv;
  }
}

__global__ __launch_bounds__(256) void scanC_kernel(
    int* __restrict__ data, const int* __restrict__ blockSums, int n) {
  int i = blockIdx.x * blockDim.x + threadIdx.x;
  if (i < n) data[i] += blockSums[i >> 10];
}

// ---------------- placement: (col,val) pairs sorted by row -------------------
__global__ __launch_bounds__(256) void place_kernel(
    const int* __restrict__ rows, const int* __restrict__ cols,
    const float* __restrict__ vals, int* __restrict__ offs,
    int2* __restrict__ sev, int E) {
  int i = blockIdx.x * blockDim.x + threadIdx.x;
  int stride = gridDim.x * blockDim.x;
  for (; i < E; i += stride) {
    int r = rows[i];
    int pos = atomicAdd(&offs[r], 1);
    int2 p;
    p.x = cols[i];
    p.y = __builtin_bit_cast(int, vals[i]);
    sev[pos] = p;
  }
}

// ---------------- gather-reduce: one wave per output row --------------------
__global__ __launch_bounds__(256) void accum_kernel(
    const ushort* __restrict__ h, const int2* __restrict__ sev,
    const int* __restrict__ offs, float* __restrict__ out, int M) {
  int wid = (int)((blockIdx.x * (size_t)blockDim.x + threadIdx.x) >> 6);
  if (wid >= M) return;
  const int lane = threadIdx.x & 63;

  int start = wid ? offs[wid - 1] : 0;
  int end = offs[wid];

  float4 acc = make_float4(0.f, 0.f, 0.f, 0.f);
  int e = start;
  for (; e + 1 < end; e += 2) {
    int2 e0 = sev[e], e1 = sev[e + 1];
    float v0 = __builtin_bit_cast(float, e0.y);
    float v1 = __builtin_bit_cast(float, e1.y);
    ushort4 h0 = *reinterpret_cast<const ushort4*>(h + (size_t)e0.x * NOUT + lane * 4);
    ushort4 h1 = *reinterpret_cast<const ushort4*>(h + (size_t)e1.x * NOUT + lane * 4);
    acc.x += v0 * bf2f(h0.x); acc.y += v0 * bf2f(h0.y);
    acc.z += v0 * bf2f(h0.z); acc.w += v0 * bf2f(h0.w);
    acc.x += v1 * bf2f(h1.x); acc.y += v1 * bf2f(h1.y);
    acc.z += v1 * bf2f(h1.z); acc.w += v1 * bf2f(h1.w);
  }
  if (e < end) {
    int2 e0 = sev[e];
    float v0 = __builtin_bit_cast(float, e0.y);
    ushort4 h0 = *reinterpret_cast<const ushort4*>(h + (size_t)e0.x * NOUT + lane * 4);
    acc.x += v0 * bf2f(h0.x); acc.y += v0 * bf2f(h0.y);
    acc.z += v0 * bf2f(h0.z); acc.w += v0 * bf2f(h0.w);
  }
  *reinterpret_cast<float4*>(out + (size_t)wid * NOUT + lane * 4) = acc;
}

extern "C" void kernel_launch(void* const* d_in, const int* in_sizes, int n_in,
                              void* d_out, int out_size, void* d_ws, size_t ws_size,
                              hipStream_t stream) {
  const float* x        = (const float*)d_in[0];
  const int*   adj_rows = (const int*)d_in[1];
  const int*   adj_cols = (const int*)d_in[2];
  const float* adj_vals = (const float*)d_in[3];
  const float* W        = (const float*)d_in[4];
  const float* b        = (const float*)d_in[5];
  float* out = (float*)d_out;

  const int M = in_sizes[0] / NIN;   // 100000
  const int E = in_sizes[1];         // 3200000

  // workspace layout
  ushort* h = (ushort*)d_ws;                       // M*NOUT bf16 (51.2 MB)
  int2*   sev = (int2*)(h + (size_t)M * NOUT);     // E int2 (25.6 MB)
  int*    offs = (int*)(sev + E);                  // M+1 ints
  const int scanBlocks = (M + 1023) / 1024;        // 98
  int*    blockSums = offs + (M + 1);              // scanBlocks ints

  gemm_kernel<<<(M + 127) / 128, 512, 0, stream>>>(x, W, b, h, M);

  hipMemsetAsync(offs, 0, (size_t)(M + 1 + scanBlocks + 8) * sizeof(int), stream);
  hist_kernel<<<2048, 256, 0, stream>>>(adj_rows, offs, E);
  scanA_kernel<<<scanBlocks, 256, 0, stream>>>(offs, blockSums, M);
  scanA_kernel<<<1, 256, 0, stream>>>(blockSums, nullptr, scanBlocks);
  scanC_kernel<<<(M + 255) / 256, 256, 0, stream>>>(offs, blockSums, M);
  place_kernel<<<2048, 256, 0, stream>>>(adj_rows, adj_cols, adj_vals, offs,
                                         sev, E);
  int ablocks = (int)(((size_t)M * 64 + 255) / 256);
  accum_kernel<<<ablocks, 256, 0, stream>>>(h, sev, offs, out, M);
}